// Round 5
// baseline (489.719 us; speedup 1.0000x reference)
//
#include <hip/hip_runtime.h>
#include <math.h>

// DeepMMD round 5: per-QUARTER pipeline to kill register spill.
// Rounds 3/4: compiler pins 84 VGPRs (6 waves/EU) regardless of
// waves_per_eu attr -> spills (WRITE_SIZE 41-227MB scratch). Fix: shrink
// per-thread live state below 84: for each 32-col quarter of the 128x128
// tile run {MFMA acc(16) -> phase F da(16) -> epilogue}, nothing big
// coexists. LDS 26.7KB -> 6 blocks/CU.

#define N_S 4096
#define LOG2E 1.4426950408889634

typedef _Float16 v8h __attribute__((ext_vector_type(8)));
typedef float v16f __attribute__((ext_vector_type(16)));
typedef float v2f __attribute__((ext_vector_type(2)));

union U16 { uint4 u; v8h h; };

// wave-internal LDS sync (lanes in lockstep; drain this wave's ds ops)
#define WAVE_LDS_SYNC() do {                                   \
    __builtin_amdgcn_wave_barrier();                           \
    asm volatile("s_waitcnt lgkmcnt(0)" ::: "memory");         \
    __builtin_amdgcn_wave_barrier();                           \
} while (0)

// ---------------- MLP: 256 blocks x 256 thr, 32 rows/block, k-split 8 ----------------
// Also zeroes D8[8192] + S[4] (replaces the memset dispatch).
__global__ __launch_bounds__(256)
void mlp_kernel(const float* __restrict__ X, const float* __restrict__ Y,
                const float* __restrict__ W1, const float* __restrict__ b1,
                const float* __restrict__ W2, const float* __restrict__ b2,
                const float* __restrict__ W3, const float* __restrict__ b3,
                const float* __restrict__ W4, const float* __restrict__ b4,
                const float* __restrict__ sq,
                float* __restrict__ featsT, float* __restrict__ wOrg,
                float* __restrict__ D8, double* __restrict__ S)
{
    __shared__ double sh[32 * 8 * 11];   // [row][chunk][z0..z9, nrm]
    int tid = threadIdx.x;
    int gtid = blockIdx.x * 256 + tid;
    if (gtid < 8192) D8[gtid] = 0.0f;
    if (gtid < 4) S[gtid] = 0.0;

    int kk = tid & 7, r8 = tid >> 3;
    int row = blockIdx.x * 32 + r8;
    const float* xr = (row < N_S) ? (X + (size_t)row * 256) : (Y + (size_t)(row - N_S) * 256);

    double z[10];
#pragma unroll
    for (int j = 0; j < 10; ++j) z[j] = 0.0;
    double nrm = 0.0;
    for (int k4 = 0; k4 < 8; ++k4) {
        int kbase = kk * 32 + k4 * 4;
        float4 xv4 = *(const float4*)(xr + kbase);
        double xv[4] = {(double)xv4.x, (double)xv4.y, (double)xv4.z, (double)xv4.w};
#pragma unroll
        for (int u = 0; u < 4; ++u) {
            nrm += xv[u] * xv[u];
#pragma unroll
            for (int j = 0; j < 10; ++j) z[j] += xv[u] * (double)W1[(kbase + u) * 10 + j];
        }
    }
    double* slot = sh + (size_t)(r8 * 8 + kk) * 11;
#pragma unroll
    for (int j = 0; j < 10; ++j) slot[j] = z[j];
    slot[10] = nrm;
    __syncthreads();

    if (tid < 32) {
        int r = blockIdx.x * 32 + tid;
        double zz[10], nr = 0.0;
#pragma unroll
        for (int j = 0; j < 10; ++j) zz[j] = (double)b1[j];
        for (int s = 0; s < 8; ++s) {
            const double* p = sh + (size_t)(tid * 8 + s) * 11;
#pragma unroll
            for (int j = 0; j < 10; ++j) zz[j] += p[j];
            nr += p[10];
        }
#pragma unroll
        for (int j = 0; j < 10; ++j) zz[j] = fmax(zz[j], 0.0) + log1p(exp(-fabs(zz[j])));

        double z2[10];
#pragma unroll
        for (int j = 0; j < 10; ++j) z2[j] = (double)b2[j];
#pragma unroll
        for (int k = 0; k < 10; ++k)
#pragma unroll
            for (int j = 0; j < 10; ++j) z2[j] += zz[k] * (double)W2[k * 10 + j];
#pragma unroll
        for (int j = 0; j < 10; ++j) z2[j] = fmax(z2[j], 0.0) + log1p(exp(-fabs(z2[j])));

        double z3[10];
#pragma unroll
        for (int j = 0; j < 10; ++j) z3[j] = (double)b3[j];
#pragma unroll
        for (int k = 0; k < 10; ++k)
#pragma unroll
            for (int j = 0; j < 10; ++j) z3[j] += z2[k] * (double)W3[k * 10 + j];
#pragma unroll
        for (int j = 0; j < 10; ++j) z3[j] = fmax(z3[j], 0.0) + log1p(exp(-fabs(z3[j])));

        for (int j = 0; j < 50; ++j) {
            double f = (double)b4[j];
#pragma unroll
            for (int k = 0; k < 10; ++k) f += z3[k] * (double)W4[k * 50 + j];
            featsT[(size_t)j * 8192 + r] = (float)f;
        }
        featsT[(size_t)50 * 8192 + r] = 0.0f;
        featsT[(size_t)51 * 8192 + r] = 0.0f;

        double sqv = (double)sq[0];
        wOrg[r] = (float)exp2(-nr * (LOG2E / (sqv * sqv)));
    }
}

// ---------------- helpers ----------------
__device__ __forceinline__ v8h ldfrag(const uint4* buf, int s, int g) {
    U16 t; t.u = buf[s * 5 + g];   // stride-5 granule rows -> even bank-quad spread
    return t.h;
}

__device__ __forceinline__ void cvt_split(float4 f0, float4 f1, uint4* hi, uint4* lo) {
    U16 H, L;
    float fv[8] = {f0.x, f0.y, f0.z, f0.w, f1.x, f1.y, f1.z, f1.w};
#pragma unroll
    for (int u = 0; u < 8; ++u) {
        _Float16 h = (_Float16)fv[u];
        H.h[u] = h;
        L.h[u] = (_Float16)(fv[u] - (float)h);
    }
    *hi = H.u; *lo = L.u;
}

// ---------------- joint pairwise pass (per-quarter pipeline) ----------------
__global__ __launch_bounds__(256)
void pair_kernel(const float* __restrict__ X, const float* __restrict__ Y,
                 const float* __restrict__ featsT, const float* __restrict__ wOrg,
                 const float* __restrict__ ep, const float* __restrict__ sq,
                 const float* __restrict__ sph,
                 float* __restrict__ D8, double* __restrict__ S)
{
    // LDS: phase A: Ahi/Alo 640 u4 + Bhi/Blo 160 u4 = 25600 B
    //      phase F: FA 26x132 f32 (13728) + FBq 26x36 (3744) = 17472
    //      epilogue: EB 4 waves x 16x36 f32 (2304) @17472 -> ends 26688
    __shared__ __align__(16) char smem[26688];

    int tid = threadIdx.x;
    int lane = tid & 63, w = tid >> 6;
    int h = lane >> 5, l31 = lane & 31, l15 = lane & 15, rg = lane >> 4;

    // upper-triangle tile decode
    int L = blockIdx.x, it = 0, span = 64;
    while (L >= span) { L -= span; --span; ++it; }
    int jt = it + L;

    bool sameHalf = (jt < 32) || (it >= 32);
    bool isDiag = (it == jt);
    bool isTrace = (jt == it + 32);
    int region = (jt < 32) ? 0 : ((it >= 32) ? 1 : 2);
    float sgn = sameHalf ? 1.0f : -1.0f;
    int i0 = it * 128, j0 = jt * 128;
    const float* aorg = (it < 32) ? X + (size_t)i0 * 256 : Y + (size_t)(i0 - N_S) * 256;
    const float* borg = (jt < 32) ? X + (size_t)j0 * 256 : Y + (size_t)(j0 - N_S) * 256;

    double epd = (double)ep[0];
    double eps = 1.0 / (1.0 + exp(-epd));
    double sqv = (double)sq[0], spv = (double)sph[0];
    float cf = (float)(LOG2E / (spv * spv));
    float twoco = (float)(2.0 * LOG2E / (sqv * sqv));
    float epsv = (float)eps, ome = (float)(1.0 - eps);

    uint4* Ahi = (uint4*)smem;
    uint4* Alo = Ahi + 640;
    uint4* Bhi = Ahi + 1280;
    uint4* Blo = Ahi + 1440;
    float* FA  = (float*)smem;                        // 26 x 132
    float* FBq = (float*)(smem + 13728);              // 26 x 36
    float* EB  = (float*)(smem + 17472 + w * 2304);   // 16 x 36 wave-private

    double bsum = 0.0, trd = 0.0;
    int frow = 32 * w + rg * 8;

    for (int qt = 0; qt < 4; ++qt) {
        int j0q = j0 + 32 * qt;
        const float* borgq = borg + (size_t)(32 * qt) * 256;

        // ---- phase A: fp16-split MFMA; wave w rows [32w,+32) x quarter cols ----
        v16f acc = (v16f)(0.0f);
        for (int kb = 0; kb < 256; kb += 32) {
            __syncthreads();
            for (int idx = tid; idx < 640; idx += 256) {
                uint4 hi, lo;
                if (idx < 512) {
                    int r = idx >> 2, g = idx & 3;
                    const float* pa = aorg + (size_t)r * 256 + kb + g * 8;
                    cvt_split(*(const float4*)pa, *(const float4*)(pa + 4), &hi, &lo);
                    Ahi[r * 5 + g] = hi; Alo[r * 5 + g] = lo;
                } else {
                    int t = idx - 512;
                    int r = t >> 2, g = t & 3;
                    const float* pb = borgq + (size_t)r * 256 + kb + g * 8;
                    cvt_split(*(const float4*)pb, *(const float4*)(pb + 4), &hi, &lo);
                    Bhi[r * 5 + g] = hi; Blo[r * 5 + g] = lo;
                }
            }
            __syncthreads();
#pragma unroll
            for (int ks = 0; ks < 2; ++ks) {
                int g = ks * 2 + h;
                int rs = 32 * w + l31;
                v8h ah = ldfrag(Ahi, rs, g);
                v8h al = ldfrag(Alo, rs, g);
                v8h bh = ldfrag(Bhi, l31, g);
                v8h bl = ldfrag(Blo, l31, g);
                acc = __builtin_amdgcn_mfma_f32_32x32x16_f16(al, bh, acc, 0, 0, 0);
                acc = __builtin_amdgcn_mfma_f32_32x32x16_f16(ah, bl, acc, 0, 0, 0);
                acc = __builtin_amdgcn_mfma_f32_32x32x16_f16(ah, bh, acc, 0, 0, 0);
            }
        }
        __syncthreads();   // MFMA frag reads done before F staging overwrites

        // ---- phase F: exact fp32 feature distances for this quarter ----
        v2f da[8];
#pragma unroll
        for (int i = 0; i < 8; ++i) da[i] = (v2f)(0.0f);

        for (int c0f = 0; c0f < 52; c0f += 26) {
            if (c0f) __syncthreads();   // chunk-1 reads done before restage
            for (int idx = tid; idx < 1040; idx += 256) {
                if (idx < 832) {
                    int k = idx >> 5, cg = (idx & 31) * 4;
                    *(float4*)&FA[k * 132 + cg] =
                        *(const float4*)&featsT[(size_t)(c0f + k) * 8192 + i0 + cg];
                } else {
                    int t = idx - 832;
                    int k = t >> 3, cg = (t & 7) * 4;
                    *(float4*)&FBq[k * 36 + cg] =
                        *(const float4*)&featsT[(size_t)(c0f + k) * 8192 + j0q + cg];
                }
            }
            __syncthreads();
            for (int k = 0; k < 26; ++k) {
                float4 a0 = *(const float4*)&FA[k * 132 + frow];
                float4 a1 = *(const float4*)&FA[k * 132 + frow + 4];
                float2 bv = *(const float2*)&FBq[k * 36 + l15 * 2];
                v2f b; b[0] = bv.x; b[1] = bv.y;
                float av[8] = {a0.x, a0.y, a0.z, a0.w, a1.x, a1.y, a1.z, a1.w};
#pragma unroll
                for (int i = 0; i < 8; ++i) {
                    v2f ai; ai[0] = av[i]; ai[1] = av[i];
                    v2f t = ai - b;
                    da[i] = t * t + da[i];
                }
            }
        }
#pragma unroll
        for (int i = 0; i < 8; ++i) {
            da[i][0] = exp2f(-da[i][0] * cf);
            da[i][1] = exp2f(-da[i][1] * cf);
        }

        // ---- epilogue (wave-private EB; no block barriers) ----
        float colacc = 0.0f;
        float wb = wOrg[j0q + l31];
#pragma unroll
        for (int r = 0; r < 2; ++r) {
            WAVE_LDS_SYNC();
            if ((rg >> 1) == r) {
                int rbase = (rg & 1) * 8;
#pragma unroll
                for (int i = 0; i < 8; ++i) {
                    float2 v; v.x = da[i][0]; v.y = da[i][1];
                    *(float2*)&EB[(rbase + i) * 36 + l15 * 2] = v;
                }
            }
            WAVE_LDS_SYNC();
#pragma unroll
            for (int q = 0; q < 8; ++q) {
                int reg = 8 * r + q;
                int row_local = (q & 3) + 8 * (q >> 2) + 4 * h;
                int tile_row = 32 * w + 16 * r + row_local;
                float waq = wOrg[i0 + tile_row];
                float e2 = EB[row_local * 36 + l31];
                float kv = waq * wb * exp2f(acc[reg] * twoco) * (ome * e2 + epsv);
                bool diagHit = (tile_row == 32 * qt + l31);
                if (isDiag && diagHit) kv = 0.0f;
                if (isTrace && diagHit) trd += (double)kv;
                bsum += (double)kv;
                colacc += kv;
                float rsum = kv;
#pragma unroll
                for (int m = 1; m < 32; m <<= 1) rsum += __shfl_xor(rsum, m, 64);
                if (l31 == q) atomicAdd(&D8[i0 + tile_row], sgn * rsum);
            }
            WAVE_LDS_SYNC();
        }

        if (!isDiag) {
            float v = colacc + __shfl_xor(colacc, 32, 64);
            if (h == 0) atomicAdd(&D8[j0q + l31], sgn * v);
        }
    }

    // total sum (+trace)
#pragma unroll
    for (int m = 1; m < 64; m <<= 1) bsum += __shfl_xor(bsum, m, 64);
    if (lane == 0) {
        double wgt = (sameHalf && !isDiag) ? 2.0 : 1.0;
        atomicAdd(&S[region], wgt * bsum);
    }
    if (isTrace) {
#pragma unroll
        for (int m = 1; m < 64; m <<= 1) trd += __shfl_xor(trd, m, 64);
        if (lane == 0) atomicAdd(&S[3], trd);
    }
}

// ---------------- final scalar assembly ----------------
__global__ __launch_bounds__(256)
void final_kernel(const float* __restrict__ D8, const double* __restrict__ S,
                  float* __restrict__ out)
{
    __shared__ double buf[512];
    int tid = threadIdx.x;
    double sD = 0, sD2 = 0;
    for (int i = tid; i < 4096; i += 256) {
        double d = (double)D8[i] + (double)D8[i + 4096];
        sD += d; sD2 += d * d;
    }
    buf[tid] = sD; buf[256 + tid] = sD2;
    __syncthreads();
    for (int s = 128; s > 0; s >>= 1) {
        if (tid < s) { buf[tid] += buf[tid + s]; buf[256 + tid] += buf[256 + tid + s]; }
        __syncthreads();
    }
    if (tid == 0) {
        double n = (double)N_S, D = n * (n - 1.0);
        double xx = S[0] / D, yy = S[1] / D, xy = (S[2] - S[3]) / D;
        double mmd2 = xx - 2.0 * xy + yy;
        double sumd = buf[0], sumd2 = buf[256];
        double sumh = 2.0 * n + sumd;                    // hs_i = 2 + delta_i
        double sumhs2 = 4.0 * n + 4.0 * sumd + sumd2;
        double n3 = n * n * n, n4 = n3 * n;
        double var = 4.0 / n3 * sumhs2 - 4.0 / n4 * sumh * sumh + 1e-8;
        out[0] = (float)mmd2;
        out[1] = (float)var;
    }
}

extern "C" void kernel_launch(void* const* d_in, const int* in_sizes, int n_in,
                              void* d_out, int out_size, void* d_ws, size_t ws_size,
                              hipStream_t stream)
{
    const float* X   = (const float*)d_in[0];
    const float* Y   = (const float*)d_in[1];
    const float* W1  = (const float*)d_in[2];
    const float* b1  = (const float*)d_in[3];
    const float* W2  = (const float*)d_in[4];
    const float* b2  = (const float*)d_in[5];
    const float* W3  = (const float*)d_in[6];
    const float* b3  = (const float*)d_in[7];
    const float* W4  = (const float*)d_in[8];
    const float* b4  = (const float*)d_in[9];
    const float* ep  = (const float*)d_in[10];
    const float* sq  = (const float*)d_in[11];
    const float* sph = (const float*)d_in[12];
    float* out = (float*)d_out;

    char* ws = (char*)d_ws;
    float*  featsT = (float*)ws;                      // 52*8192*4 = 1703936
    float*  wOrg   = (float*)(ws + 1703936);          // 32768
    float*  D8     = (float*)(ws + 1736704);          // 32768
    double* S      = (double*)(ws + 1769472);         // 32 (Sxx, Syy, Sxy, trace)

    mlp_kernel<<<256, 256, 0, stream>>>(X, Y, W1, b1, W2, b2, W3, b3, W4, b4,
                                        sq, featsT, wOrg, D8, S);

    pair_kernel<<<2080, 256, 0, stream>>>(X, Y, featsT, wOrg, ep, sq, sph, D8, S);

    final_kernel<<<1, 256, 0, stream>>>(D8, S, out);
}

// Round 6
// 383.945 us; speedup vs baseline: 1.2755x; 1.2755x over previous
//
#include <hip/hip_runtime.h>
#include <math.h>

// DeepMMD round 6:
//  - single-product fp16 MFMA for the org dot (RMS error analysis: dG~1.4e-3
//    -> e1 rel err 5e-6, budget 3e-4; the r1 hi/lo split used a wrong
//    worst-case-aligned bound). fp16 conversion PRECOMPUTED in mlp_kernel (Zh),
//    so pair staging has zero cvt VALU.
//  - phase F computed directly in MFMA C-layout (rows 32w+4h+{0..3}+8j,
//    cols 32c+l31): no LDS e2 round-trip, no epilogue barriers, F reads
//    straight from global (L1 broadcast/coalesced).
//  - per column-half pipeline: acc(32)+da(32) -> peak ~100 VGPR;
//    __launch_bounds__(256,2) (the only config that granted >=128, round 2).
//  - LDS 27648B: [row][9 granules] stride-9 (odd) -> conflict-minimal b128.

#define N_S 4096
#define LOG2E 1.4426950408889634

typedef _Float16 v8h __attribute__((ext_vector_type(8)));
typedef float v16f __attribute__((ext_vector_type(16)));
typedef float v2f __attribute__((ext_vector_type(2)));

union U16 { uint4 u; v8h h; };

// ---------------- MLP: 256 blocks x 256 thr, 32 rows/block, k-split 8 ----------------
// Writes featsT[50][8192] fp32, Zh[8192][256] fp16, wOrg[8192]; zeroes D8, S.
__global__ __launch_bounds__(256)
void mlp_kernel(const float* __restrict__ X, const float* __restrict__ Y,
                const float* __restrict__ W1, const float* __restrict__ b1,
                const float* __restrict__ W2, const float* __restrict__ b2,
                const float* __restrict__ W3, const float* __restrict__ b3,
                const float* __restrict__ W4, const float* __restrict__ b4,
                const float* __restrict__ sq,
                float* __restrict__ featsT, _Float16* __restrict__ Zh,
                float* __restrict__ wOrg,
                float* __restrict__ D8, double* __restrict__ S)
{
    __shared__ double sh[32 * 8 * 11];   // [row][chunk][z0..z9, nrm]
    int tid = threadIdx.x;
    int gtid = blockIdx.x * 256 + tid;
    if (gtid < 8192) D8[gtid] = 0.0f;
    if (gtid < 4) S[gtid] = 0.0;

    int kk = tid & 7, r8 = tid >> 3;
    int row = blockIdx.x * 32 + r8;
    const float* xr = (row < N_S) ? (X + (size_t)row * 256) : (Y + (size_t)(row - N_S) * 256);

    double z[10];
#pragma unroll
    for (int j = 0; j < 10; ++j) z[j] = 0.0;
    double nrm = 0.0;
    for (int k4 = 0; k4 < 8; ++k4) {
        int kbase = kk * 32 + k4 * 4;
        float4 xv4 = *(const float4*)(xr + kbase);
        // fp16 copy of the org data (consumed by pair staging, no cvt there)
        union { _Float16 h[4]; uint2 u; } cv;
        cv.h[0] = (_Float16)xv4.x; cv.h[1] = (_Float16)xv4.y;
        cv.h[2] = (_Float16)xv4.z; cv.h[3] = (_Float16)xv4.w;
        *(uint2*)&Zh[(size_t)row * 256 + kbase] = cv.u;

        double xv[4] = {(double)xv4.x, (double)xv4.y, (double)xv4.z, (double)xv4.w};
#pragma unroll
        for (int u = 0; u < 4; ++u) {
            nrm += xv[u] * xv[u];
#pragma unroll
            for (int j = 0; j < 10; ++j) z[j] += xv[u] * (double)W1[(kbase + u) * 10 + j];
        }
    }
    double* slot = sh + (size_t)(r8 * 8 + kk) * 11;
#pragma unroll
    for (int j = 0; j < 10; ++j) slot[j] = z[j];
    slot[10] = nrm;
    __syncthreads();

    if (tid < 32) {
        int r = blockIdx.x * 32 + tid;
        double zz[10], nr = 0.0;
#pragma unroll
        for (int j = 0; j < 10; ++j) zz[j] = (double)b1[j];
        for (int s = 0; s < 8; ++s) {
            const double* p = sh + (size_t)(tid * 8 + s) * 11;
#pragma unroll
            for (int j = 0; j < 10; ++j) zz[j] += p[j];
            nr += p[10];
        }
#pragma unroll
        for (int j = 0; j < 10; ++j) zz[j] = fmax(zz[j], 0.0) + log1p(exp(-fabs(zz[j])));

        double z2[10];
#pragma unroll
        for (int j = 0; j < 10; ++j) z2[j] = (double)b2[j];
#pragma unroll
        for (int k = 0; k < 10; ++k)
#pragma unroll
            for (int j = 0; j < 10; ++j) z2[j] += zz[k] * (double)W2[k * 10 + j];
#pragma unroll
        for (int j = 0; j < 10; ++j) z2[j] = fmax(z2[j], 0.0) + log1p(exp(-fabs(z2[j])));

        double z3[10];
#pragma unroll
        for (int j = 0; j < 10; ++j) z3[j] = (double)b3[j];
#pragma unroll
        for (int k = 0; k < 10; ++k)
#pragma unroll
            for (int j = 0; j < 10; ++j) z3[j] += z2[k] * (double)W3[k * 10 + j];
#pragma unroll
        for (int j = 0; j < 10; ++j) z3[j] = fmax(z3[j], 0.0) + log1p(exp(-fabs(z3[j])));

        for (int j = 0; j < 50; ++j) {
            double f = (double)b4[j];
#pragma unroll
            for (int k = 0; k < 10; ++k) f += z3[k] * (double)W4[k * 50 + j];
            featsT[(size_t)j * 8192 + r] = (float)f;
        }
        double sqv = (double)sq[0];
        wOrg[r] = (float)exp2(-nr * (LOG2E / (sqv * sqv)));
    }
}

// ---------------- joint pairwise pass ----------------
__global__ __launch_bounds__(256, 2)
void pair_kernel(const _Float16* __restrict__ Zh, const float* __restrict__ featsT,
                 const float* __restrict__ wOrg,
                 const float* __restrict__ ep, const float* __restrict__ sq,
                 const float* __restrict__ sph,
                 float* __restrict__ D8, double* __restrict__ S)
{
    // LDS: Ah 128 rows x 9 granules x 16B = 18432 | Bh 64 x 9 x 16 = 9216
    __shared__ __align__(16) char smem[27648];
    uint4* Ah = (uint4*)smem;
    uint4* Bh = Ah + 1152;

    int tid = threadIdx.x;
    int lane = tid & 63, w = tid >> 6;
    int h = lane >> 5, l31 = lane & 31;

    // upper-triangle tile decode
    int L = blockIdx.x, it = 0, span = 64;
    while (L >= span) { L -= span; --span; ++it; }
    int jt = it + L;

    bool sameHalf = (jt < 32) || (it >= 32);
    bool isDiag = (it == jt);
    bool isTrace = (jt == it + 32);
    int region = (jt < 32) ? 0 : ((it >= 32) ? 1 : 2);
    float sgn = sameHalf ? 1.0f : -1.0f;
    int i0 = it * 128, j0 = jt * 128;

    double epd = (double)ep[0];
    double eps = 1.0 / (1.0 + exp(-epd));
    double sqv = (double)sq[0], spv = (double)sph[0];
    float cf = (float)(LOG2E / (spv * spv));
    float twoco = (float)(2.0 * LOG2E / (sqv * sqv));
    float epsv = (float)eps, ome = (float)(1.0 - eps);

    const _Float16* Arow = Zh + (size_t)i0 * 256;
    double bsum = 0.0, trd = 0.0;
    int fa_base = i0 + 32 * w + 4 * h;

    for (int hf = 0; hf < 2; ++hf) {
        const _Float16* Brow = Zh + (size_t)(j0 + 64 * hf) * 256;

        // ---- phase A: fp16 MFMA org dot (wave w: 32 rows x this half's 64 cols) ----
        v16f acc0 = (v16f)(0.0f), acc1 = (v16f)(0.0f);
        for (int kb = 0; kb < 256; kb += 64) {
            __syncthreads();   // also protects prior half's frag reads
            for (int idx = tid; idx < 1536; idx += 256) {
                if (idx < 1024) {
                    int r = idx >> 3, g = idx & 7;
                    Ah[r * 9 + g] = *(const uint4*)(Arow + (size_t)r * 256 + kb + g * 8);
                } else {
                    int t = idx - 1024;
                    int r = t >> 3, g = t & 7;
                    Bh[r * 9 + g] = *(const uint4*)(Brow + (size_t)r * 256 + kb + g * 8);
                }
            }
            __syncthreads();
#pragma unroll
            for (int ks = 0; ks < 4; ++ks) {
                int g = 2 * ks + h;
                U16 ta, tb0, tb1;
                ta.u  = Ah[(32 * w + l31) * 9 + g];
                tb0.u = Bh[l31 * 9 + g];
                tb1.u = Bh[(32 + l31) * 9 + g];
                acc0 = __builtin_amdgcn_mfma_f32_32x32x16_f16(ta.h, tb0.h, acc0, 0, 0, 0);
                acc1 = __builtin_amdgcn_mfma_f32_32x32x16_f16(ta.h, tb1.h, acc1, 0, 0, 0);
            }
        }

        // ---- phase F: exact fp32 feature dist, C-layout aligned, global direct ----
        v2f da[16];
#pragma unroll
        for (int q = 0; q < 16; ++q) da[q] = (v2f)(0.0f);
        for (int k = 0; k < 50; ++k) {
            const float* fr = featsT + (size_t)k * 8192;
            float4 a0 = *(const float4*)(fr + fa_base);
            float4 a1 = *(const float4*)(fr + fa_base + 8);
            float4 a2 = *(const float4*)(fr + fa_base + 16);
            float4 a3 = *(const float4*)(fr + fa_base + 24);
            v2f b; b[0] = fr[j0 + 64 * hf + l31]; b[1] = fr[j0 + 64 * hf + 32 + l31];
            float av[16] = {a0.x, a0.y, a0.z, a0.w, a1.x, a1.y, a1.z, a1.w,
                            a2.x, a2.y, a2.z, a2.w, a3.x, a3.y, a3.z, a3.w};
#pragma unroll
            for (int q = 0; q < 16; ++q) {
                v2f ai; ai[0] = av[q]; ai[1] = av[q];
                v2f t = ai - b;
                da[q] = t * t + da[q];
            }
        }

        // ---- epilogue: no LDS, no barriers ----
        float wb0 = wOrg[j0 + 64 * hf + l31];
        float wb1 = wOrg[j0 + 64 * hf + 32 + l31];
        float cacc0 = 0.0f, cacc1 = 0.0f;
#pragma unroll
        for (int q = 0; q < 16; ++q) {
            int row = 32 * w + 4 * h + (q & 3) + 8 * (q >> 2);
            float wa = wOrg[i0 + row];
            float e20 = exp2f(-da[q][0] * cf);
            float e21 = exp2f(-da[q][1] * cf);
            float kv0 = wa * wb0 * exp2f(acc0[q] * twoco) * (ome * e20 + epsv);
            float kv1 = wa * wb1 * exp2f(acc1[q] * twoco) * (ome * e21 + epsv);
            int col0 = 64 * hf + l31, col1 = col0 + 32;
            if (isDiag) { if (row == col0) kv0 = 0.0f; if (row == col1) kv1 = 0.0f; }
            if (isTrace) { if (row == col0) trd += (double)kv0;
                           if (row == col1) trd += (double)kv1; }
            bsum += (double)kv0 + (double)kv1;
            cacc0 += kv0; cacc1 += kv1;
            float rsum = kv0 + kv1;
#pragma unroll
            for (int m = 1; m < 32; m <<= 1) rsum += __shfl_xor(rsum, m, 64);
            if (l31 == q) atomicAdd(&D8[i0 + row], sgn * rsum);
        }
        if (!isDiag) {
            float c0 = cacc0 + __shfl_xor(cacc0, 32, 64);
            float c1 = cacc1 + __shfl_xor(cacc1, 32, 64);
            if (h == 0) {
                atomicAdd(&D8[j0 + 64 * hf + l31], sgn * c0);
                atomicAdd(&D8[j0 + 64 * hf + 32 + l31], sgn * c1);
            }
        }
    }

    // block totals
#pragma unroll
    for (int m = 1; m < 64; m <<= 1) bsum += __shfl_xor(bsum, m, 64);
    __shared__ double wred[4];
    if (lane == 0) wred[w] = bsum;
    __syncthreads();
    if (tid == 0) {
        double wgt = (sameHalf && !isDiag) ? 2.0 : 1.0;
        atomicAdd(&S[region], wgt * (wred[0] + wred[1] + wred[2] + wred[3]));
    }
    if (isTrace) {
#pragma unroll
        for (int m = 1; m < 64; m <<= 1) trd += __shfl_xor(trd, m, 64);
        if (lane == 0) atomicAdd(&S[3], trd);
    }
}

// ---------------- final scalar assembly ----------------
__global__ __launch_bounds__(256)
void final_kernel(const float* __restrict__ D8, const double* __restrict__ S,
                  float* __restrict__ out)
{
    __shared__ double buf[512];
    int tid = threadIdx.x;
    double sD = 0, sD2 = 0;
    for (int i = tid; i < 4096; i += 256) {
        double d = (double)D8[i] + (double)D8[i + 4096];
        sD += d; sD2 += d * d;
    }
    buf[tid] = sD; buf[256 + tid] = sD2;
    __syncthreads();
    for (int s = 128; s > 0; s >>= 1) {
        if (tid < s) { buf[tid] += buf[tid + s]; buf[256 + tid] += buf[256 + tid + s]; }
        __syncthreads();
    }
    if (tid == 0) {
        double n = (double)N_S, D = n * (n - 1.0);
        double xx = S[0] / D, yy = S[1] / D, xy = (S[2] - S[3]) / D;
        double mmd2 = xx - 2.0 * xy + yy;
        double sumd = buf[0], sumd2 = buf[256];
        double sumh = 2.0 * n + sumd;                    // hs_i = 2 + delta_i
        double sumhs2 = 4.0 * n + 4.0 * sumd + sumd2;
        double n3 = n * n * n, n4 = n3 * n;
        double var = 4.0 / n3 * sumhs2 - 4.0 / n4 * sumh * sumh + 1e-8;
        out[0] = (float)mmd2;
        out[1] = (float)var;
    }
}

extern "C" void kernel_launch(void* const* d_in, const int* in_sizes, int n_in,
                              void* d_out, int out_size, void* d_ws, size_t ws_size,
                              hipStream_t stream)
{
    const float* X   = (const float*)d_in[0];
    const float* Y   = (const float*)d_in[1];
    const float* W1  = (const float*)d_in[2];
    const float* b1  = (const float*)d_in[3];
    const float* W2  = (const float*)d_in[4];
    const float* b2  = (const float*)d_in[5];
    const float* W3  = (const float*)d_in[6];
    const float* b3  = (const float*)d_in[7];
    const float* W4  = (const float*)d_in[8];
    const float* b4  = (const float*)d_in[9];
    const float* ep  = (const float*)d_in[10];
    const float* sq  = (const float*)d_in[11];
    const float* sph = (const float*)d_in[12];
    float* out = (float*)d_out;

    char* ws = (char*)d_ws;
    float*     featsT = (float*)ws;                   // 50*8192*4 = 1638400
    _Float16*  Zh     = (_Float16*)(ws + 1638400);    // 8192*256*2 = 4194304
    float*     wOrg   = (float*)(ws + 5832704);       // 32768
    float*     D8     = (float*)(ws + 5865472);       // 32768
    double*    S      = (double*)(ws + 5898240);      // 32 (Sxx, Syy, Sxy, trace)

    mlp_kernel<<<256, 256, 0, stream>>>(X, Y, W1, b1, W2, b2, W3, b3, W4, b4,
                                        sq, featsT, Zh, wOrg, D8, S);

    pair_kernel<<<2080, 256, 0, stream>>>(Zh, featsT, wOrg, ep, sq, sph, D8, S);

    final_kernel<<<1, 256, 0, stream>>>(D8, S, out);
}